// Round 2
// baseline (2035.058 us; speedup 1.0000x reference)
//
#include <hip/hip_runtime.h>

#define N_TX   500000
#define N_ACC  100000
#define E_CNT  1000000
#define D_TX   64
#define D_ACC  32
#define H_DIM  64

#define SCAN_B    256
#define SCAN_I    8
#define SCAN_TILE (SCAN_B * SCAN_I)                         // 2048
#define NSCAN_BLOCKS ((N_TX + SCAN_TILE - 1) / SCAN_TILE)   // 245

#define TROWS 16                    // x-tile rows staged per step
#define TFL4  (TROWS * H_DIM / 4)   // 256 float4 per tile

// ---- CSR build ------------------------------------------------------------

__global__ __launch_bounds__(256) void hist_kernel(
    const int* __restrict__ dst, int* __restrict__ cnt) {
    int e = blockIdx.x * blockDim.x + threadIdx.x;
    if (e < E_CNT) atomicAdd(&cnt[dst[e]], 1);
}

__global__ __launch_bounds__(SCAN_B) void scan1_kernel(
    const int* __restrict__ cnt, int* __restrict__ offs, int* __restrict__ bsum) {
    __shared__ int lds[SCAN_B];
    int base = blockIdx.x * SCAN_TILE + threadIdx.x * SCAN_I;
    int v[SCAN_I];
    int tsum = 0;
#pragma unroll
    for (int i = 0; i < SCAN_I; ++i) {
        int idx = base + i;
        v[i] = (idx < N_TX) ? cnt[idx] : 0;
        tsum += v[i];
    }
    lds[threadIdx.x] = tsum;
    __syncthreads();
    for (int off = 1; off < SCAN_B; off <<= 1) {
        int a = 0;
        if ((int)threadIdx.x >= off) a = lds[threadIdx.x - off];
        __syncthreads();
        lds[threadIdx.x] += a;
        __syncthreads();
    }
    int texcl = lds[threadIdx.x] - tsum;
    if (threadIdx.x == SCAN_B - 1) bsum[blockIdx.x] = lds[SCAN_B - 1];
    int run = texcl;
#pragma unroll
    for (int i = 0; i < SCAN_I; ++i) {
        int idx = base + i;
        if (idx < N_TX) offs[idx] = run;
        run += v[i];
    }
}

__global__ __launch_bounds__(256) void scan2_kernel(int* __restrict__ bsum, int nb) {
    __shared__ int lds[256];
    int t = threadIdx.x;
    int v = (t < nb) ? bsum[t] : 0;
    lds[t] = v;
    __syncthreads();
    for (int off = 1; off < 256; off <<= 1) {
        int a = 0;
        if (t >= off) a = lds[t - off];
        __syncthreads();
        lds[t] += a;
        __syncthreads();
    }
    if (t < nb) bsum[t] = lds[t] - v;  // exclusive
}

__global__ __launch_bounds__(256) void finalize_kernel(
    int* __restrict__ offs, int* __restrict__ cursors, const int* __restrict__ bsum) {
    int i = blockIdx.x * blockDim.x + threadIdx.x;
    if (i < N_TX) {
        int f = offs[i] + bsum[i / SCAN_TILE];
        offs[i] = f;
        cursors[i] = f;
    }
}

__global__ __launch_bounds__(256) void fill_kernel(
    const int* __restrict__ src, const int* __restrict__ dst,
    int* __restrict__ cursors, int* __restrict__ eidx) {
    int e = blockIdx.x * blockDim.x + threadIdx.x;
    if (e < E_CNT) {
        int d = dst[e];
        int p = atomicAdd(&cursors[d], 1);
        eidx[p] = src[e];
    }
}

// ---- y = x_acc @ Wl -------------------------------------------------------
__global__ __launch_bounds__(256, 4) void acc_transform_kernel(
    const float* __restrict__ x_acc, const float* __restrict__ Wl,
    float* __restrict__ y, int rows_per_wave) {
    int lane = threadIdx.x & 63;
    int wave = (blockIdx.x * blockDim.x + threadIdx.x) >> 6;
    float wl[D_ACC];
#pragma unroll
    for (int k = 0; k < D_ACC; ++k) wl[k] = Wl[k * H_DIM + lane];
#pragma unroll
    for (int k = 0; k < D_ACC; ++k) asm volatile("" : "+v"(wl[k]));  // pin
    int r0 = wave * rows_per_wave;
    int r1 = min(r0 + rows_per_wave, N_ACC);
    for (int row = r0; row < r1; ++row) {
        int urow = __builtin_amdgcn_readfirstlane(row);
        const float4* xr = (const float4*)(x_acc + (size_t)urow * D_ACC);
        float a0 = 0.f, a1 = 0.f, a2 = 0.f, a3 = 0.f;
#pragma unroll
        for (int q = 0; q < 8; ++q) {
            float4 v = xr[q];
            a0 = fmaf(v.x, wl[4 * q + 0], a0);
            a1 = fmaf(v.y, wl[4 * q + 1], a1);
            a2 = fmaf(v.z, wl[4 * q + 2], a2);
            a3 = fmaf(v.w, wl[4 * q + 3], a3);
        }
        y[(size_t)urow * H_DIM + lane] = (a0 + a1) + (a2 + a3);
    }
}

// ---- Fused row kernel -----------------------------------------------------
// One wave per 64-row chunk; lane = output channel.
// CSR metadata for all 64 rows batched in one coalesced pass + first-4-edge
// prefetch (v_readlane broadcast inside the loop, no memory chain).
// x_tx staged through a wave-private double-buffered LDS tile (16 rows):
//   issue coalesced global loads for tile t+1 -> regs, compute tile t from
//   LDS broadcast ds_read_b128, then vmcnt-drain + ds_write tile t+1.
// This takes the ~900cy HBM miss latency of the x row reads off the per-row
// critical path (it hides under ~2000cy of tile compute).
__global__ __launch_bounds__(256, 4) void row_kernel(
    const float* __restrict__ x_tx,
    const float* __restrict__ y,
    const int*   __restrict__ offs,
    const int*   __restrict__ cnt,
    const int*   __restrict__ eidx,
    const float* __restrict__ Wr,    // [D_TX][H]
    const float* __restrict__ bl,    // [H]
    const float* __restrict__ Wout,  // [H]
    const float* __restrict__ bout,  // [1]
    float*       __restrict__ logits,
    float*       __restrict__ txx) {
    __shared__ float xs[4 * 2 * TROWS * H_DIM];  // 4 waves * double buffer * 4KB = 32 KB

    int lane = threadIdx.x & 63;
    int wib  = threadIdx.x >> 6;
    int wave = (blockIdx.x * blockDim.x + threadIdx.x) >> 6;

    int rbase = wave * 64;
    if (rbase >= N_TX) return;
    int nrows = min(64, N_TX - rbase);

    float* xbuf0 = xs + wib * (2 * TROWS * H_DIM);
    float* xbuf1 = xbuf0 + TROWS * H_DIM;

    float wr[D_TX];
#pragma unroll
    for (int k = 0; k < D_TX; ++k) wr[k] = Wr[k * H_DIM + lane];
#pragma unroll
    for (int k = 0; k < D_TX; ++k) asm volatile("" : "+v"(wr[k]));  // pin
    float b  = bl[lane];
    float wo = Wout[lane];
    float bo = bout[0];
    asm volatile("" : "+v"(b), "+v"(wo), "+v"(bo));

    // --- batched CSR metadata: lane i holds row rbase+i ---
    int deg_l = 0, off_l = 0;
    if (lane < nrows) {
        deg_l = cnt[rbase + lane];
        off_l = offs[rbase + lane];
    }
    int s0_l = 0, s1_l = 0, s2_l = 0, s3_l = 0;
    if (deg_l > 0) s0_l = eidx[off_l];
    if (deg_l > 1) s1_l = eidx[off_l + 1];
    if (deg_l > 2) s2_l = eidx[off_l + 2];
    if (deg_l > 3) s3_l = eidx[off_l + 3];

    int ubase = __builtin_amdgcn_readfirstlane(rbase);
    const float4* xsrc = (const float4*)(x_tx + (size_t)ubase * D_TX);  // 1024 float4 / chunk

    // stage tile 0
    float4 st[4];
#pragma unroll
    for (int j = 0; j < 4; ++j) {
        int f  = j * 64 + lane;
        int gr = ubase + (f >> 4);
        if (gr < N_TX) st[j] = xsrc[f];
        else           st[j] = make_float4(0.f, 0.f, 0.f, 0.f);
    }
    {
        float4* db = (float4*)xbuf0;
#pragma unroll
        for (int j = 0; j < 4; ++j) db[j * 64 + lane] = st[j];
    }

    for (int t = 0; t < 4; ++t) {
        float* cur = (t & 1) ? xbuf1 : xbuf0;

        // issue next tile's global loads early (latency hides under compute)
        if (t < 3) {
#pragma unroll
            for (int j = 0; j < 4; ++j) {
                int f  = (t + 1) * TFL4 + j * 64 + lane;
                int gr = ubase + (f >> 4);
                if (gr < N_TX) st[j] = xsrc[f];
                else           st[j] = make_float4(0.f, 0.f, 0.f, 0.f);
            }
        }

        int kend = min(TROWS, nrows - t * TROWS);
        for (int kk = 0; kk < kend; ++kk) {
            int k   = t * TROWS + kk;
            int urow = ubase + k;
            int deg = __builtin_amdgcn_readlane(deg_l, k);
            int off = __builtin_amdgcn_readlane(off_l, k);
            int s0  = __builtin_amdgcn_readlane(s0_l, k);
            int s1  = __builtin_amdgcn_readlane(s1_l, k);
            int s2  = __builtin_amdgcn_readlane(s2_l, k);
            int s3  = __builtin_amdgcn_readlane(s3_l, k);

            // issue prefetched gathers up front (uniform base + lane offset)
            float v0 = 0.f, v1 = 0.f, v2 = 0.f, v3 = 0.f;
            if (deg > 0) v0 = y[(size_t)s0 * H_DIM + lane];
            if (deg > 1) v1 = y[(size_t)s1 * H_DIM + lane];
            if (deg > 2) v2 = y[(size_t)s2 * H_DIM + lane];
            if (deg > 3) v3 = y[(size_t)s3 * H_DIM + lane];

            // dense: x row from LDS broadcast (conflict-free, lgkmcnt-pipelined)
            const float4* xr = (const float4*)(cur + kk * H_DIM);
            float a0 = 0.f, a1 = 0.f, a2 = 0.f, a3 = 0.f;
#pragma unroll
            for (int q = 0; q < 16; ++q) {
                float4 xv = xr[q];
                a0 = fmaf(xv.x, wr[4 * q + 0], a0);
                a1 = fmaf(xv.y, wr[4 * q + 1], a1);
                a2 = fmaf(xv.z, wr[4 * q + 2], a2);
                a3 = fmaf(xv.w, wr[4 * q + 3], a3);
            }

            float g = (v0 + v1) + (v2 + v3);
            // rare tail: edges beyond the 4 prefetched (E[deg>4] ~ 5%)
            for (int e = 4; e < deg; ++e) {
                int se = __builtin_amdgcn_readfirstlane(eidx[off + e]);
                g += y[(size_t)se * H_DIM + lane];
            }

            float inv = 1.0f / (float)(deg > 0 ? deg : 1);
            float h = ((a0 + a1) + (a2 + a3)) + b + g * inv;
            float r = fmaxf(h, 0.f);
            txx[(size_t)urow * H_DIM + lane] = r;

            float p = r * wo;
#pragma unroll
            for (int sh = 32; sh > 0; sh >>= 1) p += __shfl_down(p, sh);
            if (lane == 0) logits[urow] = p + bo;
        }

        if (nrows <= (t + 1) * TROWS) break;

        // write next tile after compute (vmcnt drain lands here, T14 style)
        if (t < 3) {
            float4* db = (float4*)((t & 1) ? xbuf0 : xbuf1);
#pragma unroll
            for (int j = 0; j < 4; ++j) db[j * 64 + lane] = st[j];
        }
    }
}

extern "C" void kernel_launch(void* const* d_in, const int* in_sizes, int n_in,
                              void* d_out, int out_size, void* d_ws, size_t ws_size,
                              hipStream_t stream) {
    const float* x_tx     = (const float*)d_in[0];
    const float* x_acc    = (const float*)d_in[1];
    const int*   pays_src = (const int*)d_in[2];
    const int*   pays_dst = (const int*)d_in[3];
    // d_in[4], d_in[5]: rev edges — unused (h_acc is dead in the reference)
    const float* Wl   = (const float*)d_in[6];
    const float* bl   = (const float*)d_in[7];
    const float* Wr   = (const float*)d_in[8];
    // d_in[9..11]: rev weights — unused
    const float* Wout = (const float*)d_in[12];
    const float* bout = (const float*)d_in[13];

    float* out    = (float*)d_out;
    float* logits = out;            // [N_TX]
    float* txx    = out + N_TX;     // [N_TX][H]

    // workspace layout
    int* cnt     = (int*)d_ws;           // [N_TX]
    int* offs    = cnt + N_TX;           // [N_TX]
    int* cursors = offs + N_TX;          // [N_TX]
    int* bsum    = cursors + N_TX;       // [1024 pad]
    int* eidx    = bsum + 1024;          // [E]
    float* y     = (float*)(eidx + E_CNT);  // [N_ACC][H] = 25.6 MB

    hipMemsetAsync(cnt, 0, (size_t)N_TX * sizeof(int), stream);

    hist_kernel<<<(E_CNT + 255) / 256, 256, 0, stream>>>(pays_dst, cnt);
    scan1_kernel<<<NSCAN_BLOCKS, SCAN_B, 0, stream>>>(cnt, offs, bsum);
    scan2_kernel<<<1, 256, 0, stream>>>(bsum, NSCAN_BLOCKS);
    finalize_kernel<<<(N_TX + 255) / 256, 256, 0, stream>>>(offs, cursors, bsum);
    fill_kernel<<<(E_CNT + 255) / 256, 256, 0, stream>>>(pays_src, pays_dst, cursors, eidx);

    // y = x_acc @ Wl : 2048 blocks * 4 waves = 8192 waves (13 rows/wave)
    {
        const int blocks = 2048;
        int rpw = (N_ACC + blocks * 4 - 1) / (blocks * 4);
        acc_transform_kernel<<<blocks, 256, 0, stream>>>(x_acc, Wl, y, rpw);
    }

    // fused row kernel: one wave per 64-row chunk
    {
        const int waves  = (N_TX + 63) / 64;   // 7813
        const int blocks = (waves + 3) / 4;    // 1954
        row_kernel<<<blocks, 256, 0, stream>>>(
            x_tx, y, offs, cnt, eidx, Wr, bl, Wout, bout, logits, txx);
    }
}

// Round 4
// 584.840 us; speedup vs baseline: 3.4797x; 3.4797x over previous
//
#include <hip/hip_runtime.h>

#define N_TX   500000
#define N_ACC  100000
#define E_CNT  1000000
#define D_TX   64
#define D_ACC  32
#define H_DIM  64

#define SCAN_B    256
#define SCAN_I    8
#define SCAN_TILE (SCAN_B * SCAN_I)                         // 2048
#define NSCAN_BLOCKS ((N_TX + SCAN_TILE - 1) / SCAN_TILE)   // 245

// ---- CSR build ------------------------------------------------------------

__global__ __launch_bounds__(256) void hist_kernel(
    const int* __restrict__ dst, int* __restrict__ cnt) {
    int e = blockIdx.x * blockDim.x + threadIdx.x;
    if (e < E_CNT) atomicAdd(&cnt[dst[e]], 1);
}

__global__ __launch_bounds__(SCAN_B) void scan1_kernel(
    const int* __restrict__ cnt, int* __restrict__ offs, int* __restrict__ bsum) {
    __shared__ int lds[SCAN_B];
    int base = blockIdx.x * SCAN_TILE + threadIdx.x * SCAN_I;
    int v[SCAN_I];
    int tsum = 0;
#pragma unroll
    for (int i = 0; i < SCAN_I; ++i) {
        int idx = base + i;
        v[i] = (idx < N_TX) ? cnt[idx] : 0;
        tsum += v[i];
    }
    lds[threadIdx.x] = tsum;
    __syncthreads();
    for (int off = 1; off < SCAN_B; off <<= 1) {
        int a = 0;
        if ((int)threadIdx.x >= off) a = lds[threadIdx.x - off];
        __syncthreads();
        lds[threadIdx.x] += a;
        __syncthreads();
    }
    int texcl = lds[threadIdx.x] - tsum;
    if (threadIdx.x == SCAN_B - 1) bsum[blockIdx.x] = lds[SCAN_B - 1];
    int run = texcl;
#pragma unroll
    for (int i = 0; i < SCAN_I; ++i) {
        int idx = base + i;
        if (idx < N_TX) offs[idx] = run;
        run += v[i];
    }
}

__global__ __launch_bounds__(256) void scan2_kernel(int* __restrict__ bsum, int nb) {
    __shared__ int lds[256];
    int t = threadIdx.x;
    int v = (t < nb) ? bsum[t] : 0;
    lds[t] = v;
    __syncthreads();
    for (int off = 1; off < 256; off <<= 1) {
        int a = 0;
        if (t >= off) a = lds[t - off];
        __syncthreads();
        lds[t] += a;
        __syncthreads();
    }
    if (t < nb) bsum[t] = lds[t] - v;  // exclusive
}

__global__ __launch_bounds__(256) void finalize_kernel(
    int* __restrict__ offs, int* __restrict__ cursors, const int* __restrict__ bsum) {
    int i = blockIdx.x * blockDim.x + threadIdx.x;
    if (i < N_TX) {
        int f = offs[i] + bsum[i / SCAN_TILE];
        offs[i] = f;
        cursors[i] = f;
    }
}

__global__ __launch_bounds__(256) void fill_kernel(
    const int* __restrict__ src, const int* __restrict__ dst,
    int* __restrict__ cursors, int* __restrict__ eidx) {
    int e = blockIdx.x * blockDim.x + threadIdx.x;
    if (e < E_CNT) {
        int d = dst[e];
        int p = atomicAdd(&cursors[d], 1);
        eidx[p] = src[e];
    }
}

// ---- y = x_acc @ Wl -------------------------------------------------------
__global__ __launch_bounds__(256, 4) void acc_transform_kernel(
    const float* __restrict__ x_acc, const float* __restrict__ Wl,
    float* __restrict__ y, int rows_per_wave) {
    int lane = threadIdx.x & 63;
    int wave = (blockIdx.x * blockDim.x + threadIdx.x) >> 6;
    float wl[D_ACC];
#pragma unroll
    for (int k = 0; k < D_ACC; ++k) wl[k] = Wl[k * H_DIM + lane];
#pragma unroll
    for (int k = 0; k < D_ACC; ++k) asm volatile("" : "+v"(wl[k]));  // pin
    int r0 = wave * rows_per_wave;
    int r1 = min(r0 + rows_per_wave, N_ACC);
    for (int row = r0; row < r1; ++row) {
        int urow = __builtin_amdgcn_readfirstlane(row);
        const float4* xr = (const float4*)(x_acc + (size_t)urow * D_ACC);
        float a0 = 0.f, a1 = 0.f, a2 = 0.f, a3 = 0.f;
#pragma unroll
        for (int q = 0; q < 8; ++q) {
            float4 v = xr[q];
            a0 = fmaf(v.x, wl[4 * q + 0], a0);
            a1 = fmaf(v.y, wl[4 * q + 1], a1);
            a2 = fmaf(v.z, wl[4 * q + 2], a2);
            a3 = fmaf(v.w, wl[4 * q + 3], a3);
        }
        y[(size_t)urow * H_DIM + lane] = (a0 + a1) + (a2 + a3);
    }
}

// ---- Fused row kernel -----------------------------------------------------
// One wave per 64-row chunk; lane = output channel.
// CSR metadata for all 64 rows batched in one coalesced pass + first-4-edge
// prefetch (v_readlane broadcast inside the loop, no memory chain).
// Rows processed in PAIRS: both rows' x-loads and y-gathers issue as one
// batch, halving the serial HBM-latency chains per wave. launch_bounds
// (256,2) raises the VGPR cap to 256 so the pair state stays in registers
// (the (256,4)=128 cap is what caused the R2 scratch-spill disaster:
// FETCH 246MB -> 2.7GB).
__global__ __launch_bounds__(256, 2) void row_kernel(
    const float* __restrict__ x_tx,
    const float* __restrict__ y,
    const int*   __restrict__ offs,
    const int*   __restrict__ cnt,
    const int*   __restrict__ eidx,
    const float* __restrict__ Wr,    // [D_TX][H]
    const float* __restrict__ bl,    // [H]
    const float* __restrict__ Wout,  // [H]
    const float* __restrict__ bout,  // [1]
    float*       __restrict__ logits,
    float*       __restrict__ txx) {
    int lane = threadIdx.x & 63;
    int wave = (blockIdx.x * blockDim.x + threadIdx.x) >> 6;

    int rbase = wave * 64;
    if (rbase >= N_TX) return;
    int nrows = min(64, N_TX - rbase);

    float wr[D_TX];
#pragma unroll
    for (int k = 0; k < D_TX; ++k) wr[k] = Wr[k * H_DIM + lane];
#pragma unroll
    for (int k = 0; k < D_TX; ++k) asm volatile("" : "+v"(wr[k]));  // pin
    float b  = bl[lane];
    float wo = Wout[lane];
    float bo = bout[0];
    asm volatile("" : "+v"(b), "+v"(wo), "+v"(bo));

    // --- batched CSR metadata: lane i holds row rbase+i ---
    int deg_l = 0, off_l = 0;
    if (lane < nrows) {
        deg_l = cnt[rbase + lane];
        off_l = offs[rbase + lane];
    }
    int s0_l = 0, s1_l = 0, s2_l = 0, s3_l = 0;
    if (deg_l > 0) s0_l = eidx[off_l];
    if (deg_l > 1) s1_l = eidx[off_l + 1];
    if (deg_l > 2) s2_l = eidx[off_l + 2];
    if (deg_l > 3) s3_l = eidx[off_l + 3];
    int inv_il = __float_as_int(1.0f / (float)(deg_l > 0 ? deg_l : 1));

    int ubase = __builtin_amdgcn_readfirstlane(rbase);

    // all chunks have even nrows (64, last = 32), but guard anyway
    for (int k = 0; k < nrows; k += 2) {
        bool hasB = (k + 1 < nrows);
        int urA = ubase + k;
        int urB = ubase + k + 1;

        int degA = __builtin_amdgcn_readlane(deg_l, k);
        int offA = __builtin_amdgcn_readlane(off_l, k);
        int s0A  = __builtin_amdgcn_readlane(s0_l, k);
        int s1A  = __builtin_amdgcn_readlane(s1_l, k);
        int s2A  = __builtin_amdgcn_readlane(s2_l, k);
        int s3A  = __builtin_amdgcn_readlane(s3_l, k);
        float invA = __int_as_float(__builtin_amdgcn_readlane(inv_il, k));

        int kB = hasB ? (k + 1) : k;
        int degB = hasB ? __builtin_amdgcn_readlane(deg_l, kB) : 0;
        int offB = __builtin_amdgcn_readlane(off_l, kB);
        int s0B  = __builtin_amdgcn_readlane(s0_l, kB);
        int s1B  = __builtin_amdgcn_readlane(s1_l, kB);
        int s2B  = __builtin_amdgcn_readlane(s2_l, kB);
        int s3B  = __builtin_amdgcn_readlane(s3_l, kB);
        float invB = __int_as_float(__builtin_amdgcn_readlane(inv_il, kB));

        // issue ALL gathers for the pair up front
        float vA0 = 0.f, vA1 = 0.f, vA2 = 0.f, vA3 = 0.f;
        float vB0 = 0.f, vB1 = 0.f, vB2 = 0.f, vB3 = 0.f;
        if (degA > 0) vA0 = y[(size_t)s0A * H_DIM + lane];
        if (degA > 1) vA1 = y[(size_t)s1A * H_DIM + lane];
        if (degA > 2) vA2 = y[(size_t)s2A * H_DIM + lane];
        if (degA > 3) vA3 = y[(size_t)s3A * H_DIM + lane];
        if (degB > 0) vB0 = y[(size_t)s0B * H_DIM + lane];
        if (degB > 1) vB1 = y[(size_t)s1B * H_DIM + lane];
        if (degB > 2) vB2 = y[(size_t)s2B * H_DIM + lane];
        if (degB > 3) vB3 = y[(size_t)s3B * H_DIM + lane];

        // dense: both rows' x loads interleave -> one latency chain per pair
        const float4* xrA = (const float4*)(x_tx + (size_t)urA * D_TX);
        const float4* xrB = (const float4*)(x_tx + (size_t)(hasB ? urB : urA) * D_TX);
        float aA0 = 0.f, aA1 = 0.f, aA2 = 0.f, aA3 = 0.f;
        float aB0 = 0.f, aB1 = 0.f, aB2 = 0.f, aB3 = 0.f;
#pragma unroll
        for (int q = 0; q < 16; ++q) {
            float4 xa = xrA[q];
            float4 xb = xrB[q];
            aA0 = fmaf(xa.x, wr[4 * q + 0], aA0);
            aA1 = fmaf(xa.y, wr[4 * q + 1], aA1);
            aA2 = fmaf(xa.z, wr[4 * q + 2], aA2);
            aA3 = fmaf(xa.w, wr[4 * q + 3], aA3);
            aB0 = fmaf(xb.x, wr[4 * q + 0], aB0);
            aB1 = fmaf(xb.y, wr[4 * q + 1], aB1);
            aB2 = fmaf(xb.z, wr[4 * q + 2], aB2);
            aB3 = fmaf(xb.w, wr[4 * q + 3], aB3);
        }

        float gA = (vA0 + vA1) + (vA2 + vA3);
        float gB = (vB0 + vB1) + (vB2 + vB3);
        // rare tail: edges beyond the 4 prefetched (~5% of rows)
        for (int e = 4; e < degA; ++e) {
            int se = __builtin_amdgcn_readfirstlane(eidx[offA + e]);
            gA += y[(size_t)se * H_DIM + lane];
        }
        for (int e = 4; e < degB; ++e) {
            int se = __builtin_amdgcn_readfirstlane(eidx[offB + e]);
            gB += y[(size_t)se * H_DIM + lane];
        }

        float hA = ((aA0 + aA1) + (aA2 + aA3)) + b + gA * invA;
        float rA = fmaxf(hA, 0.f);
        txx[(size_t)urA * H_DIM + lane] = rA;
        float pA = rA * wo;
#pragma unroll
        for (int sh = 32; sh > 0; sh >>= 1) pA += __shfl_down(pA, sh);
        if (lane == 0) logits[urA] = pA + bo;

        if (hasB) {
            float hB = ((aB0 + aB1) + (aB2 + aB3)) + b + gB * invB;
            float rB = fmaxf(hB, 0.f);
            txx[(size_t)urB * H_DIM + lane] = rB;
            float pB = rB * wo;
#pragma unroll
            for (int sh = 32; sh > 0; sh >>= 1) pB += __shfl_down(pB, sh);
            if (lane == 0) logits[urB] = pB + bo;
        }
    }
}

extern "C" void kernel_launch(void* const* d_in, const int* in_sizes, int n_in,
                              void* d_out, int out_size, void* d_ws, size_t ws_size,
                              hipStream_t stream) {
    const float* x_tx     = (const float*)d_in[0];
    const float* x_acc    = (const float*)d_in[1];
    const int*   pays_src = (const int*)d_in[2];
    const int*   pays_dst = (const int*)d_in[3];
    // d_in[4], d_in[5]: rev edges — unused (h_acc is dead in the reference)
    const float* Wl   = (const float*)d_in[6];
    const float* bl   = (const float*)d_in[7];
    const float* Wr   = (const float*)d_in[8];
    // d_in[9..11]: rev weights — unused
    const float* Wout = (const float*)d_in[12];
    const float* bout = (const float*)d_in[13];

    float* out    = (float*)d_out;
    float* logits = out;            // [N_TX]
    float* txx    = out + N_TX;     // [N_TX][H]

    // workspace layout
    int* cnt     = (int*)d_ws;           // [N_TX]
    int* offs    = cnt + N_TX;           // [N_TX]
    int* cursors = offs + N_TX;          // [N_TX]
    int* bsum    = cursors + N_TX;       // [1024 pad]
    int* eidx    = bsum + 1024;          // [E]
    float* y     = (float*)(eidx + E_CNT);  // [N_ACC][H] = 25.6 MB

    hipMemsetAsync(cnt, 0, (size_t)N_TX * sizeof(int), stream);

    hist_kernel<<<(E_CNT + 255) / 256, 256, 0, stream>>>(pays_dst, cnt);
    scan1_kernel<<<NSCAN_BLOCKS, SCAN_B, 0, stream>>>(cnt, offs, bsum);
    scan2_kernel<<<1, 256, 0, stream>>>(bsum, NSCAN_BLOCKS);
    finalize_kernel<<<(N_TX + 255) / 256, 256, 0, stream>>>(offs, cursors, bsum);
    fill_kernel<<<(E_CNT + 255) / 256, 256, 0, stream>>>(pays_src, pays_dst, cursors, eidx);

    // y = x_acc @ Wl : 2048 blocks * 4 waves = 8192 waves (13 rows/wave)
    {
        const int blocks = 2048;
        int rpw = (N_ACC + blocks * 4 - 1) / (blocks * 4);
        acc_transform_kernel<<<blocks, 256, 0, stream>>>(x_acc, Wl, y, rpw);
    }

    // fused row kernel: one wave per 64-row chunk, rows processed in pairs
    {
        const int waves  = (N_TX + 63) / 64;   // 7813
        const int blocks = (waves + 3) / 4;    // 1954
        row_kernel<<<blocks, 256, 0, stream>>>(
            x_tx, y, offs, cnt, eidx, Wr, bl, Wout, bout, logits, txx);
    }
}